// Round 14
// baseline (570.054 us; speedup 1.0000x reference)
//
#include <hip/hip_runtime.h>
#include <hip/hip_bf16.h>

// HetGTCN: hops in the 64-dim W2-projected space. Round 14:
//  - proj grid reverted to 1024 (2048 hurt: fewer tiles/block to amortize the
//    unprefetched first tile; worse W1 L2 locality).
//  - rows: TWO rows per wave — both rows' gather prologues (A+B sides = up to
//    4 independent chains) issued before any consumption. Doubles MLP for the
//    dominant deg<=8 rows; halves wave count.

typedef __attribute__((ext_vector_type(8))) short bf16x8;   // 8 bf16 (4 VGPRs)
typedef __attribute__((ext_vector_type(4))) float f32x4;

__device__ inline unsigned short f2bf(float f) {
    unsigned u = __builtin_bit_cast(unsigned, f);
    u += 0x7FFFu + ((u >> 16) & 1u);      // RNE
    return (unsigned short)(u >> 16);
}
__device__ inline float bflo(unsigned u) { return __builtin_bit_cast(float, u << 16); }
__device__ inline float bfhi(unsigned u) { return __builtin_bit_cast(float, u & 0xffff0000u); }

// barrier with LDS ordering only — does NOT drain vmcnt (prefetch stays live)
__device__ inline void bar_sync() {
    __builtin_amdgcn_sched_barrier(0);
    asm volatile("s_waitcnt lgkmcnt(0)" ::: "memory");
    __builtin_amdgcn_s_barrier();
    __builtin_amdgcn_sched_barrier(0);
}

// ---- fused: pack W1x3+W2 to bf16 MFMA B-order  AND  CSR degree count ----
__global__ void k_prep_count(const float* __restrict__ W1P, const float* __restrict__ W1A,
                             const float* __restrict__ W1S, const float* __restrict__ W2f,
                             unsigned short* __restrict__ out,
                             const int* __restrict__ pa, const int* __restrict__ ps,
                             const int* __restrict__ ap, const int* __restrict__ sp,
                             int* __restrict__ cnt, int nP, int nA, int ePA, int ePS) {
    int i = blockIdx.x * 256 + threadIdx.x;
    if (i < 3 * 65536) {
        int m = i >> 16;
        int r = i & 65535;
        int j = r & 7, l = (r >> 3) & 63, kk = (r >> 9) & 7, nt = (r >> 12) & 15;
        int col = nt * 16 + (l & 15);
        int k = kk * 32 + ((l >> 4) << 3) + j;
        const float* s = (m == 0) ? W1P : (m == 1) ? W1A : W1S;
        out[i] = f2bf(s[k * 256 + col]);
        return;
    } else if (i < 3 * 65536 + 16384) {
        int r = i - 3 * 65536;
        int j = r & 7, l = (r >> 3) & 63, kk = (r >> 9) & 7, nt = (r >> 12) & 3;
        int col = nt * 16 + (l & 15);
        int k = kk * 32 + ((l >> 4) << 3) + j;
        out[i] = f2bf(W2f[k * 64 + col]);
        return;
    }
    i -= 212992;
    int r, base;
    if (i < 0) return;
    if (i < ePA) { r = pa[i]; base = 0; }
    else if (i < ePA + ePS) { r = ps[i - ePA]; base = nP; }
    else if (i < 2 * ePA + ePS) { r = ap[i - ePA - ePS]; base = 2 * nP; }
    else if (i < 2 * ePA + 2 * ePS) { r = sp[i - 2 * ePA - ePS]; base = 2 * nP + nA; }
    else return;
    atomicAdd(&cnt[base + r], 1);
}

// ---- pipelined projection, 32-row tiles, single 16KB LDS (round-7 form) ----
__global__ __launch_bounds__(256)
void k_proj_all(const float* __restrict__ xP, const float* __restrict__ xA,
                const float* __restrict__ xS, const unsigned short* __restrict__ Wpk,
                const float* __restrict__ b1P, const float* __restrict__ b1A,
                const float* __restrict__ b1S,
                unsigned short* __restrict__ yP, unsigned short* __restrict__ yA,
                unsigned short* __restrict__ yS, int nP, int nA, int nS) {
    __shared__ unsigned short xs[32 * 256];   // 16 KiB
    const int TP = (nP + 31) >> 5, TA = (nA + 31) >> 5, TS = (nS + 31) >> 5;
    const int TT = TP + TA + TS;
    const int tid = threadIdx.x, lane = tid & 63, w = tid >> 6;
    const int l15 = lane & 15, lhi = lane >> 4;
    const unsigned short* W2pk = Wpk + 3 * 65536;

    float4 xr[8];
    int t = blockIdx.x;
    if (t >= TT) return;

    {
        const float* x; int r0, nn;
        if (t < TP) { x = xP; r0 = t << 5; nn = nP; }
        else if (t < TP + TA) { x = xA; r0 = (t - TP) << 5; nn = nA; }
        else { x = xS; r0 = (t - TP - TA) << 5; nn = nS; }
        #pragma unroll
        for (int j = 0; j < 4; ++j) {
            int c = tid + j * 256;
            int row = c >> 5, col = (c & 31) << 3;
            int gr = r0 + row;
            float4 z = make_float4(0, 0, 0, 0);
            xr[2 * j] = z; xr[2 * j + 1] = z;
            if (gr < nn) {
                const float4* p = (const float4*)(x + (size_t)gr * 256 + col);
                xr[2 * j] = p[0]; xr[2 * j + 1] = p[1];
            }
        }
    }
    while (t < TT) {
        const unsigned short* W1; const float* b1; unsigned short* y; int r0, nn;
        if (t < TP) { r0 = t << 5; nn = nP; W1 = Wpk; b1 = b1P; y = yP; }
        else if (t < TP + TA) { r0 = (t - TP) << 5; nn = nA; W1 = Wpk + 65536; b1 = b1A; y = yA; }
        else { r0 = (t - TP - TA) << 5; nn = nS; W1 = Wpk + 2 * 65536; b1 = b1S; y = yS; }

        bar_sync();   // B_pre
        #pragma unroll
        for (int j = 0; j < 4; ++j) {
            int c = tid + j * 256;
            int row = c >> 5, col = (c & 31) << 3;
            float4 f0 = xr[2 * j], f1 = xr[2 * j + 1];
            bf16x8 v;
            v[0] = (short)f2bf(f0.x); v[1] = (short)f2bf(f0.y);
            v[2] = (short)f2bf(f0.z); v[3] = (short)f2bf(f0.w);
            v[4] = (short)f2bf(f1.x); v[5] = (short)f2bf(f1.y);
            v[6] = (short)f2bf(f1.z); v[7] = (short)f2bf(f1.w);
            int byte = row * 512 + ((col * 2) ^ ((row & 7) << 4));
            *(bf16x8*)((char*)xs + byte) = v;
        }
        int tn = t + gridDim.x;
        if (tn < TT) {
            const float* x2; int r02, n2;
            if (tn < TP) { x2 = xP; r02 = tn << 5; n2 = nP; }
            else if (tn < TP + TA) { x2 = xA; r02 = (tn - TP) << 5; n2 = nA; }
            else { x2 = xS; r02 = (tn - TP - TA) << 5; n2 = nS; }
            #pragma unroll
            for (int j = 0; j < 4; ++j) {
                int c = tid + j * 256;
                int row = c >> 5, col = (c & 31) << 3;
                int gr = r02 + row;
                float4 z = make_float4(0, 0, 0, 0), a0 = z, a1 = z;
                if (gr < n2) {
                    const float4* q = (const float4*)(x2 + (size_t)gr * 256 + col);
                    a0 = q[0]; a1 = q[1];
                }
                xr[2 * j] = a0; xr[2 * j + 1] = a1;
            }
        }
        bar_sync();   // B_stage

        f32x4 acc[2][4] = {};
        #pragma unroll
        for (int kk = 0; kk < 8; ++kk) {
            int k = kk * 32 + lhi * 8;
            bf16x8 a[2], b[4];
            #pragma unroll
            for (int m = 0; m < 2; ++m) {
                int row = m * 16 + l15;
                int byte = row * 512 + ((k * 2) ^ ((row & 7) << 4));
                a[m] = *(const bf16x8*)((const char*)xs + byte);
            }
            #pragma unroll
            for (int nq = 0; nq < 4; ++nq)
                b[nq] = *(const bf16x8*)(W1 + ((((w * 4 + nq) * 8 + kk) * 64 + lane) << 3));
            #pragma unroll
            for (int m = 0; m < 2; ++m)
                #pragma unroll
                for (int nq = 0; nq < 4; ++nq)
                    acc[m][nq] = __builtin_amdgcn_mfma_f32_16x16x32_bf16(a[m], b[nq], acc[m][nq], 0, 0, 0);
        }
        bar_sync();   // B_mid

        #pragma unroll
        for (int nq = 0; nq < 4; ++nq) {
            int col = w * 64 + nq * 16 + l15;
            float bias = b1[col];
            #pragma unroll
            for (int m = 0; m < 2; ++m)
                #pragma unroll
                for (int q = 0; q < 4; ++q) {
                    int row = m * 16 + lhi * 4 + q;
                    float vv = acc[m][nq][q] + bias;
                    vv = vv > 0.f ? vv : 0.f;
                    int byte = row * 512 + ((col * 2) ^ ((row & 7) << 4));
                    *(unsigned short*)((char*)xs + byte) = f2bf(vv);
                }
        }
        bar_sync();   // B_epi

        if (w < 2) {
            f32x4 acc2[4] = {};
            #pragma unroll
            for (int kk = 0; kk < 8; ++kk) {
                int k = kk * 32 + lhi * 8;
                int row = w * 16 + l15;
                int byte = row * 512 + ((k * 2) ^ ((row & 7) << 4));
                bf16x8 a = *(const bf16x8*)((const char*)xs + byte);
                #pragma unroll
                for (int nq = 0; nq < 4; ++nq) {
                    bf16x8 b = *(const bf16x8*)(W2pk + (((nq * 8 + kk) * 64 + lane) << 3));
                    acc2[nq] = __builtin_amdgcn_mfma_f32_16x16x32_bf16(a, b, acc2[nq], 0, 0, 0);
                }
            }
            #pragma unroll
            for (int nq = 0; nq < 4; ++nq)
                #pragma unroll
                for (int q = 0; q < 4; ++q) {
                    int row = w * 16 + lhi * 4 + q;
                    int gr = r0 + row;
                    if (gr < nn) y[(size_t)gr * 64 + (nq * 16 + l15)] = f2bf(acc2[nq][q]);
                }
        }
        t = tn;
    }
}

// ======================= CSR scan/scatter =======================
__global__ __launch_bounds__(256)
void k_scan1(const int* __restrict__ cnt, int* __restrict__ off,
             int* __restrict__ bsum, int n) {
    __shared__ int sh[256];
    int tid = threadIdx.x;
    int base = blockIdx.x * 1024 + tid * 4;
    int c[4];
    #pragma unroll
    for (int j = 0; j < 4; ++j) c[j] = (base + j < n) ? cnt[base + j] : 0;
    int s = c[0] + c[1] + c[2] + c[3];
    sh[tid] = s;
    __syncthreads();
    #pragma unroll
    for (int o = 1; o < 256; o <<= 1) {
        int v = (tid >= o) ? sh[tid - o] : 0;
        __syncthreads();
        sh[tid] += v;
        __syncthreads();
    }
    int run = sh[tid] - s;
    #pragma unroll
    for (int j = 0; j < 4; ++j) {
        if (base + j < n) off[base + j] = run;
        run += c[j];
    }
    if (tid == 255) bsum[blockIdx.x] = sh[255];
}

__global__ __launch_bounds__(256)
void k_scan2(int* __restrict__ bsum, int nb) {   // nb <= 1024
    __shared__ int sh[256];
    int tid = threadIdx.x;
    int base = tid * 4;
    int v[4];
    #pragma unroll
    for (int j = 0; j < 4; ++j) v[j] = (base + j < nb) ? bsum[base + j] : 0;
    int s = v[0] + v[1] + v[2] + v[3];
    sh[tid] = s;
    __syncthreads();
    #pragma unroll
    for (int o = 1; o < 256; o <<= 1) {
        int x = (tid >= o) ? sh[tid - o] : 0;
        __syncthreads();
        sh[tid] += x;
        __syncthreads();
    }
    int run = sh[tid] - s;
    #pragma unroll
    for (int j = 0; j < 4; ++j) {
        if (base + j < nb) bsum[base + j] = run;
        run += v[j];
    }
}

__global__ void k_scan3(const int* __restrict__ off0, const int* __restrict__ bsum,
                        int* __restrict__ offPA, int* __restrict__ offPS,
                        int* __restrict__ offAP, int* __restrict__ offSP,
                        int* __restrict__ curPA, int* __restrict__ curPS,
                        int* __restrict__ curAP, int* __restrict__ curSP,
                        int nP, int nA, int nS, int ePA, int ePS) {
    int i = blockIdx.x * 256 + threadIdx.x;
    int NC = 2 * nP + nA + nS;
    if (i >= NC) return;
    int v = off0[i] + bsum[i >> 10];
    int g0, loc, ng, nE; int *og, *cg;
    if (i < nP)                { g0 = 0;           loc = i;                ng = nP; nE = ePA; og = offPA; cg = curPA; }
    else if (i < 2 * nP)       { g0 = nP;          loc = i - nP;           ng = nP; nE = ePS; og = offPS; cg = curPS; }
    else if (i < 2 * nP + nA)  { g0 = 2 * nP;      loc = i - 2 * nP;       ng = nA; nE = ePA; og = offAP; cg = curAP; }
    else                       { g0 = 2 * nP + nA; loc = i - 2 * nP - nA;  ng = nS; nE = ePS; og = offSP; cg = curSP; }
    int basev = off0[g0] + bsum[g0 >> 10];
    int rel = v - basev;
    og[loc] = rel; cg[loc] = rel;
    if (loc == 0) og[ng] = nE;
}

// XCD-affine scatter (round-11, kept)
__global__ __launch_bounds__(256)
void k_scatter_all(const int* __restrict__ pa_r, const int* __restrict__ pa_c, const float* __restrict__ pa_v,
                   const int* __restrict__ ps_r, const int* __restrict__ ps_c, const float* __restrict__ ps_v,
                   const int* __restrict__ ap_r, const int* __restrict__ ap_c, const float* __restrict__ ap_v,
                   const int* __restrict__ sp_r, const int* __restrict__ sp_c, const float* __restrict__ sp_v,
                   int* __restrict__ curPA, int* __restrict__ curPS,
                   int* __restrict__ curAP, int* __restrict__ curSP,
                   int2* __restrict__ entPA, int2* __restrict__ entPS,
                   int2* __restrict__ entAP, int2* __restrict__ entSP,
                   int nP, int nA, int nS, int ePA, int ePS) {
    int xcd = blockIdx.x & 7;
    int i = (blockIdx.x >> 3) * 256 + threadIdx.x;
    const int *r, *c; const float* v; int* cur; int2* ent; int e, n;
    if (i < ePA) { e = i; r = pa_r; c = pa_c; v = pa_v; cur = curPA; ent = entPA; n = nP; }
    else if (i < ePA + ePS) { e = i - ePA; r = ps_r; c = ps_c; v = ps_v; cur = curPS; ent = entPS; n = nP; }
    else if (i < 2 * ePA + ePS) { e = i - ePA - ePS; r = ap_r; c = ap_c; v = ap_v; cur = curAP; ent = entAP; n = nA; }
    else if (i < 2 * ePA + 2 * ePS) { e = i - 2 * ePA - ePS; r = sp_r; c = sp_c; v = sp_v; cur = curSP; ent = entSP; n = nS; }
    else return;
    int rr = __builtin_nontemporal_load(r + e);
    int r8 = rr * 8;
    if (r8 < xcd * n || r8 >= (xcd + 1) * n) return;
    int cc = __builtin_nontemporal_load(c + e);
    float vv = __builtin_nontemporal_load(v + e);
    int pp = atomicAdd(&cur[rr], 1);
    ent[pp] = make_int2(cc, __float_as_int(vv));
}

// ============== row-parallel spmm: 8 edge-slots x 8 feature-chunks ==========
__device__ inline void fma8(float acc[8], float w, uint4 g) {
    acc[0] = fmaf(w, bflo(g.x), acc[0]); acc[1] = fmaf(w, bfhi(g.x), acc[1]);
    acc[2] = fmaf(w, bflo(g.y), acc[2]); acc[3] = fmaf(w, bfhi(g.y), acc[3]);
    acc[4] = fmaf(w, bflo(g.z), acc[4]); acc[5] = fmaf(w, bfhi(g.z), acc[5]);
    acc[6] = fmaf(w, bflo(g.w), acc[6]); acc[7] = fmaf(w, bfhi(g.w), acc[7]);
}

__device__ inline void oct_pipe(const int2* __restrict__ ent, int s, int t,
                                const unsigned short* __restrict__ src,
                                int sub, int chunk, float acc[8]) {
    if (s >= t) return;
    int i0 = s + sub;
    int c0 = i0 < t ? i0 : t - 1;
    int2 Ea = ent[c0];
    float wa = i0 < t ? __int_as_float(Ea.y) : 0.f;
    uint4 ga = ((const uint4*)(src + ((size_t)(unsigned)Ea.x << 6)))[chunk];
    for (int e = s; ; ) {
        int en = e + 8;
        if (en < t) {
            int i1 = en + sub;
            int c1 = i1 < t ? i1 : t - 1;
            int2 Eb = ent[c1];
            float wb = i1 < t ? __int_as_float(Eb.y) : 0.f;
            uint4 gb = ((const uint4*)(src + ((size_t)(unsigned)Eb.x << 6)))[chunk];
            fma8(acc, wa, ga);
            wa = wb; ga = gb; e = en;
        } else {
            fma8(acc, wa, ga);
            break;
        }
    }
}

// prologue/rest split: issue a row's first gather batch without consuming it
struct OctPre { float w; uint4 g; int has; };
__device__ inline OctPre oct_pre(const int2* __restrict__ ent, int s, int t,
                                 const unsigned short* __restrict__ src,
                                 int sub, int chunk) {
    OctPre p; p.has = (s < t);
    if (p.has) {
        int i0 = s + sub;
        int c0 = i0 < t ? i0 : t - 1;
        int2 E = ent[c0];
        p.w = i0 < t ? __int_as_float(E.y) : 0.f;
        p.g = ((const uint4*)(src + ((size_t)(unsigned)E.x << 6)))[chunk];
    }
    return p;
}
__device__ inline void oct_rest(const OctPre& p, const int2* __restrict__ ent,
                                int s, int t, const unsigned short* __restrict__ src,
                                int sub, int chunk, float acc[8]) {
    if (!p.has) return;
    fma8(acc, p.w, p.g);
    if (s + 8 < t) oct_pipe(ent, s + 8, t, src, sub, chunk, acc);
}

__device__ inline void red8(float acc[8]) {
    #pragma unroll
    for (int j = 0; j < 8; ++j) {
        acc[j] += __shfl_xor(acc[j], 8, 64);
        acc[j] += __shfl_xor(acc[j], 16, 64);
        acc[j] += __shfl_xor(acc[j], 32, 64);
    }
}

__device__ inline uint4 pack8(const float acc[8]) {
    uint4 o;
    o.x = (unsigned)f2bf(acc[0]) | ((unsigned)f2bf(acc[1]) << 16);
    o.y = (unsigned)f2bf(acc[2]) | ((unsigned)f2bf(acc[3]) << 16);
    o.z = (unsigned)f2bf(acc[4]) | ((unsigned)f2bf(acc[5]) << 16);
    o.w = (unsigned)f2bf(acc[6]) | ((unsigned)f2bf(acc[7]) << 16);
    return o;
}

// fused hA + hS, TWO rows per wave (both prologues in flight before draining)
__global__ __launch_bounds__(256)
void k_rowAS(unsigned short* __restrict__ hA, const unsigned short* __restrict__ yA,
             const float* __restrict__ dAP, const int* __restrict__ offAP,
             const int2* __restrict__ entAP,
             unsigned short* __restrict__ hS, const unsigned short* __restrict__ yS,
             const float* __restrict__ dSP, const int* __restrict__ offSP,
             const int2* __restrict__ entSP,
             const unsigned short* __restrict__ srcP, int nA, int nS) {
    int wid = (blockIdx.x * 256 + threadIdx.x) >> 6;
    int lane = threadIdx.x & 63;
    int sub = lane >> 3, chunk = lane & 7;
    const int NT = nA + nS;
    int r0 = wid * 2, r1 = r0 + 1;
    if (r0 >= NT) return;
    bool v1 = r1 < NT;

    // resolve row contexts
    const int *of0, *of1 = nullptr; const int2 *en0, *en1 = nullptr;
    const unsigned short *y0, *y1 = nullptr; const float *dg0, *dg1 = nullptr;
    unsigned short *d0p, *d1p = nullptr; int l0, l1 = 0;
    if (r0 < nA) { of0 = offAP; en0 = entAP; y0 = yA; dg0 = dAP; d0p = hA; l0 = r0; }
    else         { of0 = offSP; en0 = entSP; y0 = yS; dg0 = dSP; d0p = hS; l0 = r0 - nA; }
    if (v1) {
        if (r1 < nA) { of1 = offAP; en1 = entAP; y1 = yA; dg1 = dAP; d1p = hA; l1 = r1; }
        else         { of1 = offSP; en1 = entSP; y1 = yS; dg1 = dSP; d1p = hS; l1 = r1 - nA; }
    }
    int s0 = of0[l0], t0 = of0[l0 + 1];
    int s1 = 0, t1 = 0;
    if (v1) { s1 = of1[l1]; t1 = of1[l1 + 1]; }
    float dd0 = dg0[l0];
    float dd1 = v1 ? dg1[l1] : 0.f;
    uint4 gy0 = ((const uint4*)(y0 + (size_t)l0 * 64))[chunk];
    uint4 gy1 = gy0;
    if (v1) gy1 = ((const uint4*)(y1 + (size_t)l1 * 64))[chunk];

    // issue both prologues (2 independent gather chains)
    OctPre p0 = oct_pre(en0, s0, t0, srcP, sub, chunk);
    OctPre p1 = {0.f, gy0, 0};
    if (v1) p1 = oct_pre(en1, s1, t1, srcP, sub, chunk);

    float acc0[8] = {}, acc1[8] = {};
    oct_rest(p0, en0, s0, t0, srcP, sub, chunk, acc0);
    if (v1) oct_rest(p1, en1, s1, t1, srcP, sub, chunk, acc1);

    red8(acc0);
    if (v1) red8(acc1);
    if (sub == 0) {
        acc0[0] += dd0 * bflo(gy0.x); acc0[1] += dd0 * bfhi(gy0.x);
        acc0[2] += dd0 * bflo(gy0.y); acc0[3] += dd0 * bfhi(gy0.y);
        acc0[4] += dd0 * bflo(gy0.z); acc0[5] += dd0 * bfhi(gy0.z);
        acc0[6] += dd0 * bflo(gy0.w); acc0[7] += dd0 * bfhi(gy0.w);
        ((uint4*)(d0p + (size_t)l0 * 64))[chunk] = pack8(acc0);
        if (v1) {
            acc1[0] += dd1 * bflo(gy1.x); acc1[1] += dd1 * bfhi(gy1.x);
            acc1[2] += dd1 * bflo(gy1.y); acc1[3] += dd1 * bfhi(gy1.y);
            acc1[4] += dd1 * bflo(gy1.z); acc1[5] += dd1 * bfhi(gy1.z);
            acc1[6] += dd1 * bflo(gy1.w); acc1[7] += dd1 * bfhi(gy1.w);
            ((uint4*)(d1p + (size_t)l1 * 64))[chunk] = pack8(acc1);
        }
    }
}

// hP = 0.5*((dA+dB)*yP + spmmA(srcA) + spmmB(srcB)), TWO rows per wave.
// 4 gather chains (A0,A1,B0,B1) issued before any consumption.
template<int FINAL>
__global__ __launch_bounds__(256)
void k_row2(unsigned short* __restrict__ dst, float* __restrict__ dstf,
            const unsigned short* __restrict__ yP,
            const float* __restrict__ dA, const float* __restrict__ dB,
            const int* __restrict__ offA, const int2* __restrict__ entA,
            const unsigned short* __restrict__ srcA,
            const int* __restrict__ offB, const int2* __restrict__ entB,
            const unsigned short* __restrict__ srcB,
            const float* __restrict__ b2, int n) {
    int wid = (blockIdx.x * 256 + threadIdx.x) >> 6;
    int lane = threadIdx.x & 63;
    int sub = lane >> 3, chunk = lane & 7;
    int r0 = wid * 2, r1 = r0 + 1;
    if (r0 >= n) return;
    bool v1 = r1 < n;

    int sA0 = offA[r0], tA0 = offA[r0 + 1];
    int sB0 = offB[r0], tB0 = offB[r0 + 1];
    int sA1 = 0, tA1 = 0, sB1 = 0, tB1 = 0;
    if (v1) { sA1 = offA[r1]; tA1 = offA[r1 + 1]; sB1 = offB[r1]; tB1 = offB[r1 + 1]; }
    float d0 = dA[r0] + dB[r0];
    float d1 = v1 ? (dA[r1] + dB[r1]) : 0.f;
    uint4 gy0 = ((const uint4*)(yP + (size_t)r0 * 64))[chunk];
    uint4 gy1 = gy0;
    if (v1) gy1 = ((const uint4*)(yP + (size_t)r1 * 64))[chunk];

    // 4 prologues in flight
    OctPre pA0 = oct_pre(entA, sA0, tA0, srcA, sub, chunk);
    OctPre pB0 = oct_pre(entB, sB0, tB0, srcB, sub, chunk);
    OctPre pA1 = {0.f, gy0, 0}, pB1 = {0.f, gy0, 0};
    if (v1) {
        pA1 = oct_pre(entA, sA1, tA1, srcA, sub, chunk);
        pB1 = oct_pre(entB, sB1, tB1, srcB, sub, chunk);
    }

    float acc0[8] = {}, acc1[8] = {};
    oct_rest(pA0, entA, sA0, tA0, srcA, sub, chunk, acc0);
    if (v1) oct_rest(pA1, entA, sA1, tA1, srcA, sub, chunk, acc1);
    oct_rest(pB0, entB, sB0, tB0, srcB, sub, chunk, acc0);
    if (v1) oct_rest(pB1, entB, sB1, tB1, srcB, sub, chunk, acc1);

    red8(acc0);
    if (v1) red8(acc1);
    if (sub == 0) {
        acc0[0] = 0.5f * (acc0[0] + d0 * bflo(gy0.x)); acc0[1] = 0.5f * (acc0[1] + d0 * bfhi(gy0.x));
        acc0[2] = 0.5f * (acc0[2] + d0 * bflo(gy0.y)); acc0[3] = 0.5f * (acc0[3] + d0 * bfhi(gy0.y));
        acc0[4] = 0.5f * (acc0[4] + d0 * bflo(gy0.z)); acc0[5] = 0.5f * (acc0[5] + d0 * bfhi(gy0.z));
        acc0[6] = 0.5f * (acc0[6] + d0 * bflo(gy0.w)); acc0[7] = 0.5f * (acc0[7] + d0 * bfhi(gy0.w));
        if (FINAL) {
            float4 b0v = ((const float4*)b2)[chunk * 2];
            float4 b1v = ((const float4*)b2)[chunk * 2 + 1];
            ((float4*)(dstf + (size_t)r0 * 64))[chunk * 2] =
                make_float4(acc0[0] + b0v.x, acc0[1] + b0v.y, acc0[2] + b0v.z, acc0[3] + b0v.w);
            ((float4*)(dstf + (size_t)r0 * 64))[chunk * 2 + 1] =
                make_float4(acc0[4] + b1v.x, acc0[5] + b1v.y, acc0[6] + b1v.z, acc0[7] + b1v.w);
        } else {
            ((uint4*)(dst + (size_t)r0 * 64))[chunk] = pack8(acc0);
        }
        if (v1) {
            acc1[0] = 0.5f * (acc1[0] + d1 * bflo(gy1.x)); acc1[1] = 0.5f * (acc1[1] + d1 * bfhi(gy1.x));
            acc1[2] = 0.5f * (acc1[2] + d1 * bflo(gy1.y)); acc1[3] = 0.5f * (acc1[3] + d1 * bfhi(gy1.y));
            acc1[4] = 0.5f * (acc1[4] + d1 * bflo(gy1.z)); acc1[5] = 0.5f * (acc1[5] + d1 * bfhi(gy1.z));
            acc1[6] = 0.5f * (acc1[6] + d1 * bflo(gy1.w)); acc1[7] = 0.5f * (acc1[7] + d1 * bfhi(gy1.w));
            if (FINAL) {
                float4 b0v = ((const float4*)b2)[chunk * 2];
                float4 b1v = ((const float4*)b2)[chunk * 2 + 1];
                ((float4*)(dstf + (size_t)r1 * 64))[chunk * 2] =
                    make_float4(acc1[0] + b0v.x, acc1[1] + b0v.y, acc1[2] + b0v.z, acc1[3] + b0v.w);
                ((float4*)(dstf + (size_t)r1 * 64))[chunk * 2 + 1] =
                    make_float4(acc1[4] + b1v.x, acc1[5] + b1v.y, acc1[6] + b1v.z, acc1[7] + b1v.w);
            } else {
                ((uint4*)(dst + (size_t)r1 * 64))[chunk] = pack8(acc1);
            }
        }
    }
}

extern "C" void kernel_launch(void* const* d_in, const int* in_sizes, int n_in,
                              void* d_out, int out_size, void* d_ws, size_t ws_size,
                              hipStream_t stream) {
    const float* x_P = (const float*)d_in[0];
    const float* x_A = (const float*)d_in[1];
    const float* x_S = (const float*)d_in[2];
    const int* pa_row = (const int*)d_in[3];
    const int* pa_col = (const int*)d_in[4];
    const float* pa_val = (const float*)d_in[5];
    const int* ps_row = (const int*)d_in[6];
    const int* ps_col = (const int*)d_in[7];
    const float* ps_val = (const float*)d_in[8];
    const int* ap_row = (const int*)d_in[9];
    const int* ap_col = (const int*)d_in[10];
    const float* ap_val = (const float*)d_in[11];
    const int* sp_row = (const int*)d_in[12];
    const int* sp_col = (const int*)d_in[13];
    const float* sp_val = (const float*)d_in[14];
    const float* diag_PA = (const float*)d_in[15];
    const float* diag_PS = (const float*)d_in[16];
    const float* diag_AP = (const float*)d_in[17];
    const float* diag_SP = (const float*)d_in[18];
    const float* W1_P = (const float*)d_in[19];
    const float* b1_P = (const float*)d_in[20];
    const float* W1_A = (const float*)d_in[21];
    const float* b1_A = (const float*)d_in[22];
    const float* W1_S = (const float*)d_in[23];
    const float* b1_S = (const float*)d_in[24];
    const float* W2  = (const float*)d_in[25];
    const float* b2  = (const float*)d_in[26];

    const int nP = in_sizes[15], nA = in_sizes[17], nS = in_sizes[18];
    const int ePA = in_sizes[3], ePS = in_sizes[6];
    const int NC = 2 * nP + nA + nS;

    char* base = (char*)d_ws;
    size_t cur = 0;
    auto alloc = [&](size_t bytes) -> char* {
        cur = (cur + 255) & ~(size_t)255;
        char* p = base + cur;
        cur += bytes;
        return p;
    };
    unsigned short* yP = (unsigned short*)alloc((size_t)nP * 64 * 2);
    unsigned short* yA = (unsigned short*)alloc((size_t)nA * 64 * 2);
    unsigned short* yS = (unsigned short*)alloc((size_t)nS * 64 * 2);
    unsigned short* hP = (unsigned short*)alloc((size_t)nP * 64 * 2);
    unsigned short* hA = (unsigned short*)alloc((size_t)nA * 64 * 2);
    unsigned short* hS = (unsigned short*)alloc((size_t)nS * 64 * 2);
    unsigned short* Wpk = (unsigned short*)alloc(212992 * 2);
    int* cnt  = (int*)alloc((size_t)NC * 4);
    int* off0 = (int*)alloc((size_t)NC * 4);
    int* offPA = (int*)alloc((size_t)(nP + 1) * 4);
    int* offPS = (int*)alloc((size_t)(nP + 1) * 4);
    int* offAP = (int*)alloc((size_t)(nA + 1) * 4);
    int* offSP = (int*)alloc((size_t)(nS + 1) * 4);
    int* curPA = (int*)alloc((size_t)nP * 4);
    int* curPS = (int*)alloc((size_t)nP * 4);
    int* curAP = (int*)alloc((size_t)nA * 4);
    int* curSP = (int*)alloc((size_t)nS * 4);
    int2* entPA = (int2*)alloc((size_t)ePA * 8);
    int2* entPS = (int2*)alloc((size_t)ePS * 8);
    int2* entAP = (int2*)alloc((size_t)ePA * 8);
    int2* entSP = (int2*)alloc((size_t)ePS * 8);
    int* bsum = (int*)alloc(1024 * 4);
    (void)ws_size;

    // ---- weights pack + CSR build ----
    hipMemsetAsync(cnt, 0, (size_t)NC * 4, stream);
    const int eTot = 2 * (ePA + ePS);
    k_prep_count<<<(212992 + eTot + 255) / 256, 256, 0, stream>>>(
        W1_P, W1_A, W1_S, W2, Wpk,
        pa_row, ps_row, ap_row, sp_row, cnt, nP, nA, ePA, ePS);
    const int nb = (NC + 1023) / 1024;
    k_scan1<<<nb, 256, 0, stream>>>(cnt, off0, bsum, NC);
    k_scan2<<<1, 256, 0, stream>>>(bsum, nb);
    k_scan3<<<(NC + 255) / 256, 256, 0, stream>>>(off0, bsum, offPA, offPS, offAP, offSP,
                                                  curPA, curPS, curAP, curSP,
                                                  nP, nA, nS, ePA, ePS);
    const int SCB = (eTot + 255) / 256;
    k_scatter_all<<<8 * SCB, 256, 0, stream>>>(
        pa_row, pa_col, pa_val, ps_row, ps_col, ps_val,
        ap_row, ap_col, ap_val, sp_row, sp_col, sp_val,
        curPA, curPS, curAP, curSP, entPA, entPS, entAP, entSP,
        nP, nA, nS, ePA, ePS);

    // ---- projections (round-7 pipelined persistent kernel; grid 1024) ----
    k_proj_all<<<1024, 256, 0, stream>>>(x_P, x_A, x_S, Wpk, b1_P, b1_A, b1_S,
                                         yP, yA, yS, nP, nA, nS);

    // ---- hops (2 rows/wave; hop-3 hA/hS dead -> skipped; b2 in final) ----
    const int gbP = (nP + 7) / 8, gbAS = (nA + nS + 7) / 8;
    // hop 1
    k_row2<0><<<gbP, 256, 0, stream>>>(hP, nullptr, yP, diag_PA, diag_PS,
                                       offPA, entPA, yA, offPS, entPS, yS, b2, nP);
    k_rowAS<<<gbAS, 256, 0, stream>>>(hA, yA, diag_AP, offAP, entAP,
                                      hS, yS, diag_SP, offSP, entSP, hP, nA, nS);
    // hop 2
    k_row2<0><<<gbP, 256, 0, stream>>>(hP, nullptr, yP, diag_PA, diag_PS,
                                       offPA, entPA, hA, offPS, entPS, hS, b2, nP);
    k_rowAS<<<gbAS, 256, 0, stream>>>(hA, yA, diag_AP, offAP, entAP,
                                      hS, yS, diag_SP, offSP, entSP, hP, nA, nS);
    // hop 3: only hP needed; write fp32 + b2 straight to d_out
    k_row2<1><<<gbP, 256, 0, stream>>>(nullptr, (float*)d_out, yP, diag_PA, diag_PS,
                                       offPA, entPA, hA, offPS, entPS, hS, b2, nP);
}

// Round 15
// 557.512 us; speedup vs baseline: 1.0225x; 1.0225x over previous
//
#include <hip/hip_runtime.h>
#include <hip/hip_bf16.h>

// HetGTCN: hops in the 64-dim W2-projected space. Round 15: exact revert to
// the round-11 measured optimum (559us):
//  - proj: round-7 pipelined persistent kernel (grid 1024, 16KB LDS, 4 lgkm
//    barriers, register prefetch of tile t+1 in flight across GEMMs)
//  - rows: 8 edge-slots x 8 feature-chunks, depth-2 pipelined, 1 row/wave
//  - scatter: XCD-affine row-range partition (kills 8x write amplification)
//  - CSR: fused pack+count, 3-kernel scan

typedef __attribute__((ext_vector_type(8))) short bf16x8;   // 8 bf16 (4 VGPRs)
typedef __attribute__((ext_vector_type(4))) float f32x4;

__device__ inline unsigned short f2bf(float f) {
    unsigned u = __builtin_bit_cast(unsigned, f);
    u += 0x7FFFu + ((u >> 16) & 1u);      // RNE
    return (unsigned short)(u >> 16);
}
__device__ inline float bflo(unsigned u) { return __builtin_bit_cast(float, u << 16); }
__device__ inline float bfhi(unsigned u) { return __builtin_bit_cast(float, u & 0xffff0000u); }

// barrier with LDS ordering only — does NOT drain vmcnt (prefetch stays live)
__device__ inline void bar_sync() {
    __builtin_amdgcn_sched_barrier(0);
    asm volatile("s_waitcnt lgkmcnt(0)" ::: "memory");
    __builtin_amdgcn_s_barrier();
    __builtin_amdgcn_sched_barrier(0);
}

// ---- fused: pack W1x3+W2 to bf16 MFMA B-order  AND  CSR degree count ----
__global__ void k_prep_count(const float* __restrict__ W1P, const float* __restrict__ W1A,
                             const float* __restrict__ W1S, const float* __restrict__ W2f,
                             unsigned short* __restrict__ out,
                             const int* __restrict__ pa, const int* __restrict__ ps,
                             const int* __restrict__ ap, const int* __restrict__ sp,
                             int* __restrict__ cnt, int nP, int nA, int ePA, int ePS) {
    int i = blockIdx.x * 256 + threadIdx.x;
    if (i < 3 * 65536) {
        int m = i >> 16;
        int r = i & 65535;
        int j = r & 7, l = (r >> 3) & 63, kk = (r >> 9) & 7, nt = (r >> 12) & 15;
        int col = nt * 16 + (l & 15);
        int k = kk * 32 + ((l >> 4) << 3) + j;
        const float* s = (m == 0) ? W1P : (m == 1) ? W1A : W1S;
        out[i] = f2bf(s[k * 256 + col]);
        return;
    } else if (i < 3 * 65536 + 16384) {
        int r = i - 3 * 65536;
        int j = r & 7, l = (r >> 3) & 63, kk = (r >> 9) & 7, nt = (r >> 12) & 3;
        int col = nt * 16 + (l & 15);
        int k = kk * 32 + ((l >> 4) << 3) + j;
        out[i] = f2bf(W2f[k * 64 + col]);
        return;
    }
    i -= 212992;
    int r, base;
    if (i < 0) return;
    if (i < ePA) { r = pa[i]; base = 0; }
    else if (i < ePA + ePS) { r = ps[i - ePA]; base = nP; }
    else if (i < 2 * ePA + ePS) { r = ap[i - ePA - ePS]; base = 2 * nP; }
    else if (i < 2 * ePA + 2 * ePS) { r = sp[i - 2 * ePA - ePS]; base = 2 * nP + nA; }
    else return;
    atomicAdd(&cnt[base + r], 1);
}

// ---- pipelined projection, 32-row tiles, single 16KB LDS (round-7 form) ----
__global__ __launch_bounds__(256)
void k_proj_all(const float* __restrict__ xP, const float* __restrict__ xA,
                const float* __restrict__ xS, const unsigned short* __restrict__ Wpk,
                const float* __restrict__ b1P, const float* __restrict__ b1A,
                const float* __restrict__ b1S,
                unsigned short* __restrict__ yP, unsigned short* __restrict__ yA,
                unsigned short* __restrict__ yS, int nP, int nA, int nS) {
    __shared__ unsigned short xs[32 * 256];   // 16 KiB
    const int TP = (nP + 31) >> 5, TA = (nA + 31) >> 5, TS = (nS + 31) >> 5;
    const int TT = TP + TA + TS;
    const int tid = threadIdx.x, lane = tid & 63, w = tid >> 6;
    const int l15 = lane & 15, lhi = lane >> 4;
    const unsigned short* W2pk = Wpk + 3 * 65536;

    float4 xr[8];
    int t = blockIdx.x;
    if (t >= TT) return;

    {
        const float* x; int r0, nn;
        if (t < TP) { x = xP; r0 = t << 5; nn = nP; }
        else if (t < TP + TA) { x = xA; r0 = (t - TP) << 5; nn = nA; }
        else { x = xS; r0 = (t - TP - TA) << 5; nn = nS; }
        #pragma unroll
        for (int j = 0; j < 4; ++j) {
            int c = tid + j * 256;
            int row = c >> 5, col = (c & 31) << 3;
            int gr = r0 + row;
            float4 z = make_float4(0, 0, 0, 0);
            xr[2 * j] = z; xr[2 * j + 1] = z;
            if (gr < nn) {
                const float4* p = (const float4*)(x + (size_t)gr * 256 + col);
                xr[2 * j] = p[0]; xr[2 * j + 1] = p[1];
            }
        }
    }
    while (t < TT) {
        const unsigned short* W1; const float* b1; unsigned short* y; int r0, nn;
        if (t < TP) { r0 = t << 5; nn = nP; W1 = Wpk; b1 = b1P; y = yP; }
        else if (t < TP + TA) { r0 = (t - TP) << 5; nn = nA; W1 = Wpk + 65536; b1 = b1A; y = yA; }
        else { r0 = (t - TP - TA) << 5; nn = nS; W1 = Wpk + 2 * 65536; b1 = b1S; y = yS; }

        bar_sync();   // B_pre
        #pragma unroll
        for (int j = 0; j < 4; ++j) {
            int c = tid + j * 256;
            int row = c >> 5, col = (c & 31) << 3;
            float4 f0 = xr[2 * j], f1 = xr[2 * j + 1];
            bf16x8 v;
            v[0] = (short)f2bf(f0.x); v[1] = (short)f2bf(f0.y);
            v[2] = (short)f2bf(f0.z); v[3] = (short)f2bf(f0.w);
            v[4] = (short)f2bf(f1.x); v[5] = (short)f2bf(f1.y);
            v[6] = (short)f2bf(f1.z); v[7] = (short)f2bf(f1.w);
            int byte = row * 512 + ((col * 2) ^ ((row & 7) << 4));
            *(bf16x8*)((char*)xs + byte) = v;
        }
        int tn = t + gridDim.x;
        if (tn < TT) {
            const float* x2; int r02, n2;
            if (tn < TP) { x2 = xP; r02 = tn << 5; n2 = nP; }
            else if (tn < TP + TA) { x2 = xA; r02 = (tn - TP) << 5; n2 = nA; }
            else { x2 = xS; r02 = (tn - TP - TA) << 5; n2 = nS; }
            #pragma unroll
            for (int j = 0; j < 4; ++j) {
                int c = tid + j * 256;
                int row = c >> 5, col = (c & 31) << 3;
                int gr = r02 + row;
                float4 z = make_float4(0, 0, 0, 0), a0 = z, a1 = z;
                if (gr < n2) {
                    const float4* q = (const float4*)(x2 + (size_t)gr * 256 + col);
                    a0 = q[0]; a1 = q[1];
                }
                xr[2 * j] = a0; xr[2 * j + 1] = a1;
            }
        }
        bar_sync();   // B_stage

        f32x4 acc[2][4] = {};
        #pragma unroll
        for (int kk = 0; kk < 8; ++kk) {
            int k = kk * 32 + lhi * 8;
            bf16x8 a[2], b[4];
            #pragma unroll
            for (int m = 0; m < 2; ++m) {
                int row = m * 16 + l15;
                int byte = row * 512 + ((k * 2) ^ ((row & 7) << 4));
                a[m] = *(const bf16x8*)((const char*)xs + byte);
            }
            #pragma unroll
            for (int nq = 0; nq < 4; ++nq)
                b[nq] = *(const bf16x8*)(W1 + ((((w * 4 + nq) * 8 + kk) * 64 + lane) << 3));
            #pragma unroll
            for (int m = 0; m < 2; ++m)
                #pragma unroll
                for (int nq = 0; nq < 4; ++nq)
                    acc[m][nq] = __builtin_amdgcn_mfma_f32_16x16x32_bf16(a[m], b[nq], acc[m][nq], 0, 0, 0);
        }
        bar_sync();   // B_mid

        #pragma unroll
        for (int nq = 0; nq < 4; ++nq) {
            int col = w * 64 + nq * 16 + l15;
            float bias = b1[col];
            #pragma unroll
            for (int m = 0; m < 2; ++m)
                #pragma unroll
                for (int q = 0; q < 4; ++q) {
                    int row = m * 16 + lhi * 4 + q;
                    float vv = acc[m][nq][q] + bias;
                    vv = vv > 0.f ? vv : 0.f;
                    int byte = row * 512 + ((col * 2) ^ ((row & 7) << 4));
                    *(unsigned short*)((char*)xs + byte) = f2bf(vv);
                }
        }
        bar_sync();   // B_epi

        if (w < 2) {
            f32x4 acc2[4] = {};
            #pragma unroll
            for (int kk = 0; kk < 8; ++kk) {
                int k = kk * 32 + lhi * 8;
                int row = w * 16 + l15;
                int byte = row * 512 + ((k * 2) ^ ((row & 7) << 4));
                bf16x8 a = *(const bf16x8*)((const char*)xs + byte);
                #pragma unroll
                for (int nq = 0; nq < 4; ++nq) {
                    bf16x8 b = *(const bf16x8*)(W2pk + (((nq * 8 + kk) * 64 + lane) << 3));
                    acc2[nq] = __builtin_amdgcn_mfma_f32_16x16x32_bf16(a, b, acc2[nq], 0, 0, 0);
                }
            }
            #pragma unroll
            for (int nq = 0; nq < 4; ++nq)
                #pragma unroll
                for (int q = 0; q < 4; ++q) {
                    int row = w * 16 + lhi * 4 + q;
                    int gr = r0 + row;
                    if (gr < nn) y[(size_t)gr * 64 + (nq * 16 + l15)] = f2bf(acc2[nq][q]);
                }
        }
        t = tn;
    }
}

// ======================= CSR scan/scatter =======================
__global__ __launch_bounds__(256)
void k_scan1(const int* __restrict__ cnt, int* __restrict__ off,
             int* __restrict__ bsum, int n) {
    __shared__ int sh[256];
    int tid = threadIdx.x;
    int base = blockIdx.x * 1024 + tid * 4;
    int c[4];
    #pragma unroll
    for (int j = 0; j < 4; ++j) c[j] = (base + j < n) ? cnt[base + j] : 0;
    int s = c[0] + c[1] + c[2] + c[3];
    sh[tid] = s;
    __syncthreads();
    #pragma unroll
    for (int o = 1; o < 256; o <<= 1) {
        int v = (tid >= o) ? sh[tid - o] : 0;
        __syncthreads();
        sh[tid] += v;
        __syncthreads();
    }
    int run = sh[tid] - s;
    #pragma unroll
    for (int j = 0; j < 4; ++j) {
        if (base + j < n) off[base + j] = run;
        run += c[j];
    }
    if (tid == 255) bsum[blockIdx.x] = sh[255];
}

__global__ __launch_bounds__(256)
void k_scan2(int* __restrict__ bsum, int nb) {   // nb <= 1024
    __shared__ int sh[256];
    int tid = threadIdx.x;
    int base = tid * 4;
    int v[4];
    #pragma unroll
    for (int j = 0; j < 4; ++j) v[j] = (base + j < nb) ? bsum[base + j] : 0;
    int s = v[0] + v[1] + v[2] + v[3];
    sh[tid] = s;
    __syncthreads();
    #pragma unroll
    for (int o = 1; o < 256; o <<= 1) {
        int x = (tid >= o) ? sh[tid - o] : 0;
        __syncthreads();
        sh[tid] += x;
        __syncthreads();
    }
    int run = sh[tid] - s;
    #pragma unroll
    for (int j = 0; j < 4; ++j) {
        if (base + j < nb) bsum[base + j] = run;
        run += v[j];
    }
}

__global__ void k_scan3(const int* __restrict__ off0, const int* __restrict__ bsum,
                        int* __restrict__ offPA, int* __restrict__ offPS,
                        int* __restrict__ offAP, int* __restrict__ offSP,
                        int* __restrict__ curPA, int* __restrict__ curPS,
                        int* __restrict__ curAP, int* __restrict__ curSP,
                        int nP, int nA, int nS, int ePA, int ePS) {
    int i = blockIdx.x * 256 + threadIdx.x;
    int NC = 2 * nP + nA + nS;
    if (i >= NC) return;
    int v = off0[i] + bsum[i >> 10];
    int g0, loc, ng, nE; int *og, *cg;
    if (i < nP)                { g0 = 0;           loc = i;                ng = nP; nE = ePA; og = offPA; cg = curPA; }
    else if (i < 2 * nP)       { g0 = nP;          loc = i - nP;           ng = nP; nE = ePS; og = offPS; cg = curPS; }
    else if (i < 2 * nP + nA)  { g0 = 2 * nP;      loc = i - 2 * nP;       ng = nA; nE = ePA; og = offAP; cg = curAP; }
    else                       { g0 = 2 * nP + nA; loc = i - 2 * nP - nA;  ng = nS; nE = ePS; og = offSP; cg = curSP; }
    int basev = off0[g0] + bsum[g0 >> 10];
    int rel = v - basev;
    og[loc] = rel; cg[loc] = rel;
    if (loc == 0) og[ng] = nE;
}

// XCD-affine scatter: block handles only edges whose row falls in its 1/8
// row-range (blockIdx&7); blocks round-robin over XCDs -> each ent line is
// written from ONE XCD's L2 (one writeback instead of 8).
__global__ __launch_bounds__(256)
void k_scatter_all(const int* __restrict__ pa_r, const int* __restrict__ pa_c, const float* __restrict__ pa_v,
                   const int* __restrict__ ps_r, const int* __restrict__ ps_c, const float* __restrict__ ps_v,
                   const int* __restrict__ ap_r, const int* __restrict__ ap_c, const float* __restrict__ ap_v,
                   const int* __restrict__ sp_r, const int* __restrict__ sp_c, const float* __restrict__ sp_v,
                   int* __restrict__ curPA, int* __restrict__ curPS,
                   int* __restrict__ curAP, int* __restrict__ curSP,
                   int2* __restrict__ entPA, int2* __restrict__ entPS,
                   int2* __restrict__ entAP, int2* __restrict__ entSP,
                   int nP, int nA, int nS, int ePA, int ePS) {
    int xcd = blockIdx.x & 7;
    int i = (blockIdx.x >> 3) * 256 + threadIdx.x;
    const int *r, *c; const float* v; int* cur; int2* ent; int e, n;
    if (i < ePA) { e = i; r = pa_r; c = pa_c; v = pa_v; cur = curPA; ent = entPA; n = nP; }
    else if (i < ePA + ePS) { e = i - ePA; r = ps_r; c = ps_c; v = ps_v; cur = curPS; ent = entPS; n = nP; }
    else if (i < 2 * ePA + ePS) { e = i - ePA - ePS; r = ap_r; c = ap_c; v = ap_v; cur = curAP; ent = entAP; n = nA; }
    else if (i < 2 * ePA + 2 * ePS) { e = i - 2 * ePA - ePS; r = sp_r; c = sp_c; v = sp_v; cur = curSP; ent = entSP; n = nS; }
    else return;
    int rr = __builtin_nontemporal_load(r + e);
    int r8 = rr * 8;
    if (r8 < xcd * n || r8 >= (xcd + 1) * n) return;
    int cc = __builtin_nontemporal_load(c + e);
    float vv = __builtin_nontemporal_load(v + e);
    int pp = atomicAdd(&cur[rr], 1);
    ent[pp] = make_int2(cc, __float_as_int(vv));
}

// ============== row-parallel spmm: 8 edge-slots x 8 feature-chunks ==========
__device__ inline void fma8(float acc[8], float w, uint4 g) {
    acc[0] = fmaf(w, bflo(g.x), acc[0]); acc[1] = fmaf(w, bfhi(g.x), acc[1]);
    acc[2] = fmaf(w, bflo(g.y), acc[2]); acc[3] = fmaf(w, bfhi(g.y), acc[3]);
    acc[4] = fmaf(w, bflo(g.z), acc[4]); acc[5] = fmaf(w, bfhi(g.z), acc[5]);
    acc[6] = fmaf(w, bflo(g.w), acc[6]); acc[7] = fmaf(w, bfhi(g.w), acc[7]);
}

// depth-2 pipelined 8-slot gather: issue next oct before consuming current
__device__ inline void oct_pipe(const int2* __restrict__ ent, int s, int t,
                                const unsigned short* __restrict__ src,
                                int sub, int chunk, float acc[8]) {
    if (s >= t) return;
    int i0 = s + sub;
    int c0 = i0 < t ? i0 : t - 1;
    int2 Ea = ent[c0];
    float wa = i0 < t ? __int_as_float(Ea.y) : 0.f;
    uint4 ga = ((const uint4*)(src + ((size_t)(unsigned)Ea.x << 6)))[chunk];
    for (int e = s; ; ) {
        int en = e + 8;
        if (en < t) {
            int i1 = en + sub;
            int c1 = i1 < t ? i1 : t - 1;
            int2 Eb = ent[c1];
            float wb = i1 < t ? __int_as_float(Eb.y) : 0.f;
            uint4 gb = ((const uint4*)(src + ((size_t)(unsigned)Eb.x << 6)))[chunk];
            fma8(acc, wa, ga);
            wa = wb; ga = gb; e = en;
        } else {
            fma8(acc, wa, ga);
            break;
        }
    }
}

__device__ inline void red8(float acc[8]) {
    #pragma unroll
    for (int j = 0; j < 8; ++j) {
        acc[j] += __shfl_xor(acc[j], 8, 64);
        acc[j] += __shfl_xor(acc[j], 16, 64);
        acc[j] += __shfl_xor(acc[j], 32, 64);
    }
}

__device__ inline uint4 pack8(const float acc[8]) {
    uint4 o;
    o.x = (unsigned)f2bf(acc[0]) | ((unsigned)f2bf(acc[1]) << 16);
    o.y = (unsigned)f2bf(acc[2]) | ((unsigned)f2bf(acc[3]) << 16);
    o.z = (unsigned)f2bf(acc[4]) | ((unsigned)f2bf(acc[5]) << 16);
    o.w = (unsigned)f2bf(acc[6]) | ((unsigned)f2bf(acc[7]) << 16);
    return o;
}

// fused hA + hS (both gather from hP)
__global__ __launch_bounds__(256)
void k_rowAS(unsigned short* __restrict__ hA, const unsigned short* __restrict__ yA,
             const float* __restrict__ dAP, const int* __restrict__ offAP,
             const int2* __restrict__ entAP,
             unsigned short* __restrict__ hS, const unsigned short* __restrict__ yS,
             const float* __restrict__ dSP, const int* __restrict__ offSP,
             const int2* __restrict__ entSP,
             const unsigned short* __restrict__ srcP, int nA, int nS) {
    int r = (blockIdx.x * 256 + threadIdx.x) >> 6;
    int lane = threadIdx.x & 63;
    int sub = lane >> 3, chunk = lane & 7;
    const int* off; const int2* ent; const unsigned short* y;
    const float* dg; unsigned short* dst;
    if (r < nA) { off = offAP; ent = entAP; y = yA; dg = dAP; dst = hA; }
    else if ((r -= nA) < nS) { off = offSP; ent = entSP; y = yS; dg = dSP; dst = hS; }
    else return;
    float acc[8] = {};
    int s = off[r], t = off[r + 1];
    float d = dg[r];
    uint4 gy = ((const uint4*)(y + (size_t)r * 64))[chunk];
    oct_pipe(ent, s, t, srcP, sub, chunk, acc);
    red8(acc);
    if (sub == 0) {
        acc[0] += d * bflo(gy.x); acc[1] += d * bfhi(gy.x);
        acc[2] += d * bflo(gy.y); acc[3] += d * bfhi(gy.y);
        acc[4] += d * bflo(gy.z); acc[5] += d * bfhi(gy.z);
        acc[6] += d * bflo(gy.w); acc[7] += d * bfhi(gy.w);
        ((uint4*)(dst + (size_t)r * 64))[chunk] = pack8(acc);
    }
}

// hP = 0.5*((dA+dB)*yP + spmmA(srcA) + spmmB(srcB))  [+ b2 -> fp32 out]
// B-side (PS, deg~1): its first oct issued before the A loop (latency hidden).
template<int FINAL>
__global__ __launch_bounds__(256)
void k_row2(unsigned short* __restrict__ dst, float* __restrict__ dstf,
            const unsigned short* __restrict__ yP,
            const float* __restrict__ dA, const float* __restrict__ dB,
            const int* __restrict__ offA, const int2* __restrict__ entA,
            const unsigned short* __restrict__ srcA,
            const int* __restrict__ offB, const int2* __restrict__ entB,
            const unsigned short* __restrict__ srcB,
            const float* __restrict__ b2, int n) {
    int r = (blockIdx.x * 256 + threadIdx.x) >> 6;
    int lane = threadIdx.x & 63;
    int sub = lane >> 3, chunk = lane & 7;
    if (r >= n) return;
    float acc[8] = {};
    int sA = offA[r], tA = offA[r + 1];
    int sB = offB[r], tB = offB[r + 1];
    float d = dA[r] + dB[r];
    uint4 gy = ((const uint4*)(yP + (size_t)r * 64))[chunk];

    bool hasB = sB < tB;
    float wB = 0.f; uint4 gB;
    if (hasB) {
        int iB = sB + sub;
        int cB = iB < tB ? iB : tB - 1;
        int2 EB = entB[cB];
        wB = iB < tB ? __int_as_float(EB.y) : 0.f;
        gB = ((const uint4*)(srcB + ((size_t)(unsigned)EB.x << 6)))[chunk];
    }
    oct_pipe(entA, sA, tA, srcA, sub, chunk, acc);
    if (hasB) {
        fma8(acc, wB, gB);
        if (sB + 8 < tB) oct_pipe(entB, sB + 8, tB, srcB, sub, chunk, acc);
    }
    red8(acc);
    if (sub == 0) {
        acc[0] = 0.5f * (acc[0] + d * bflo(gy.x)); acc[1] = 0.5f * (acc[1] + d * bfhi(gy.x));
        acc[2] = 0.5f * (acc[2] + d * bflo(gy.y)); acc[3] = 0.5f * (acc[3] + d * bfhi(gy.y));
        acc[4] = 0.5f * (acc[4] + d * bflo(gy.z)); acc[5] = 0.5f * (acc[5] + d * bfhi(gy.z));
        acc[6] = 0.5f * (acc[6] + d * bflo(gy.w)); acc[7] = 0.5f * (acc[7] + d * bfhi(gy.w));
        if (FINAL) {
            float4 b0 = ((const float4*)b2)[chunk * 2];
            float4 b1v = ((const float4*)b2)[chunk * 2 + 1];
            float4 o0 = make_float4(acc[0] + b0.x, acc[1] + b0.y, acc[2] + b0.z, acc[3] + b0.w);
            float4 o1 = make_float4(acc[4] + b1v.x, acc[5] + b1v.y, acc[6] + b1v.z, acc[7] + b1v.w);
            ((float4*)(dstf + (size_t)r * 64))[chunk * 2] = o0;
            ((float4*)(dstf + (size_t)r * 64))[chunk * 2 + 1] = o1;
        } else {
            ((uint4*)(dst + (size_t)r * 64))[chunk] = pack8(acc);
        }
    }
}

extern "C" void kernel_launch(void* const* d_in, const int* in_sizes, int n_in,
                              void* d_out, int out_size, void* d_ws, size_t ws_size,
                              hipStream_t stream) {
    const float* x_P = (const float*)d_in[0];
    const float* x_A = (const float*)d_in[1];
    const float* x_S = (const float*)d_in[2];
    const int* pa_row = (const int*)d_in[3];
    const int* pa_col = (const int*)d_in[4];
    const float* pa_val = (const float*)d_in[5];
    const int* ps_row = (const int*)d_in[6];
    const int* ps_col = (const int*)d_in[7];
    const float* ps_val = (const float*)d_in[8];
    const int* ap_row = (const int*)d_in[9];
    const int* ap_col = (const int*)d_in[10];
    const float* ap_val = (const float*)d_in[11];
    const int* sp_row = (const int*)d_in[12];
    const int* sp_col = (const int*)d_in[13];
    const float* sp_val = (const float*)d_in[14];
    const float* diag_PA = (const float*)d_in[15];
    const float* diag_PS = (const float*)d_in[16];
    const float* diag_AP = (const float*)d_in[17];
    const float* diag_SP = (const float*)d_in[18];
    const float* W1_P = (const float*)d_in[19];
    const float* b1_P = (const float*)d_in[20];
    const float* W1_A = (const float*)d_in[21];
    const float* b1_A = (const float*)d_in[22];
    const float* W1_S = (const float*)d_in[23];
    const float* b1_S = (const float*)d_in[24];
    const float* W2  = (const float*)d_in[25];
    const float* b2  = (const float*)d_in[26];

    const int nP = in_sizes[15], nA = in_sizes[17], nS = in_sizes[18];
    const int ePA = in_sizes[3], ePS = in_sizes[6];
    const int NC = 2 * nP + nA + nS;

    char* base = (char*)d_ws;
    size_t cur = 0;
    auto alloc = [&](size_t bytes) -> char* {
        cur = (cur + 255) & ~(size_t)255;
        char* p = base + cur;
        cur += bytes;
        return p;
    };
    unsigned short* yP = (unsigned short*)alloc((size_t)nP * 64 * 2);
    unsigned short* yA = (unsigned short*)alloc((size_t)nA * 64 * 2);
    unsigned short* yS = (unsigned short*)alloc((size_t)nS * 64 * 2);
    unsigned short* hP = (unsigned short*)alloc((size_t)nP * 64 * 2);
    unsigned short* hA = (unsigned short*)alloc((size_t)nA * 64 * 2);
    unsigned short* hS = (unsigned short*)alloc((size_t)nS * 64 * 2);
    unsigned short* Wpk = (unsigned short*)alloc(212992 * 2);
    int* cnt  = (int*)alloc((size_t)NC * 4);
    int* off0 = (int*)alloc((size_t)NC * 4);
    int* offPA = (int*)alloc((size_t)(nP + 1) * 4);
    int* offPS = (int*)alloc((size_t)(nP + 1) * 4);
    int* offAP = (int*)alloc((size_t)(nA + 1) * 4);
    int* offSP = (int*)alloc((size_t)(nS + 1) * 4);
    int* curPA = (int*)alloc((size_t)nP * 4);
    int* curPS = (int*)alloc((size_t)nP * 4);
    int* curAP = (int*)alloc((size_t)nA * 4);
    int* curSP = (int*)alloc((size_t)nS * 4);
    int2* entPA = (int2*)alloc((size_t)ePA * 8);
    int2* entPS = (int2*)alloc((size_t)ePS * 8);
    int2* entAP = (int2*)alloc((size_t)ePA * 8);
    int2* entSP = (int2*)alloc((size_t)ePS * 8);
    int* bsum = (int*)alloc(1024 * 4);
    (void)ws_size;

    // ---- weights pack + CSR build ----
    hipMemsetAsync(cnt, 0, (size_t)NC * 4, stream);
    const int eTot = 2 * (ePA + ePS);
    k_prep_count<<<(212992 + eTot + 255) / 256, 256, 0, stream>>>(
        W1_P, W1_A, W1_S, W2, Wpk,
        pa_row, ps_row, ap_row, sp_row, cnt, nP, nA, ePA, ePS);
    const int nb = (NC + 1023) / 1024;
    k_scan1<<<nb, 256, 0, stream>>>(cnt, off0, bsum, NC);
    k_scan2<<<1, 256, 0, stream>>>(bsum, nb);
    k_scan3<<<(NC + 255) / 256, 256, 0, stream>>>(off0, bsum, offPA, offPS, offAP, offSP,
                                                  curPA, curPS, curAP, curSP,
                                                  nP, nA, nS, ePA, ePS);
    const int SCB = (eTot + 255) / 256;
    k_scatter_all<<<8 * SCB, 256, 0, stream>>>(
        pa_row, pa_col, pa_val, ps_row, ps_col, ps_val,
        ap_row, ap_col, ap_val, sp_row, sp_col, sp_val,
        curPA, curPS, curAP, curSP, entPA, entPS, entAP, entSP,
        nP, nA, nS, ePA, ePS);

    // ---- projections (round-7 pipelined persistent kernel; grid 1024) ----
    k_proj_all<<<1024, 256, 0, stream>>>(x_P, x_A, x_S, Wpk, b1_P, b1_A, b1_S,
                                         yP, yA, yS, nP, nA, nS);

    // ---- hops (hop-3 hA/hS dead -> skipped; b2 fused into final) ----
    const int gbP = (nP + 3) / 4, gbAS = (nA + nS + 3) / 4;
    // hop 1
    k_row2<0><<<gbP, 256, 0, stream>>>(hP, nullptr, yP, diag_PA, diag_PS,
                                       offPA, entPA, yA, offPS, entPS, yS, b2, nP);
    k_rowAS<<<gbAS, 256, 0, stream>>>(hA, yA, diag_AP, offAP, entAP,
                                      hS, yS, diag_SP, offSP, entSP, hP, nA, nS);
    // hop 2
    k_row2<0><<<gbP, 256, 0, stream>>>(hP, nullptr, yP, diag_PA, diag_PS,
                                       offPA, entPA, hA, offPS, entPS, hS, b2, nP);
    k_rowAS<<<gbAS, 256, 0, stream>>>(hA, yA, diag_AP, offAP, entAP,
                                      hS, yS, diag_SP, offSP, entSP, hP, nA, nS);
    // hop 3: only hP needed; write fp32 + b2 straight to d_out
    k_row2<1><<<gbP, 256, 0, stream>>>(nullptr, (float*)d_out, yP, diag_PA, diag_PS,
                                       offPA, entPA, hA, offPS, entPS, hS, b2, nP);
}